// Round 1
// baseline (68.704 us; speedup 1.0000x reference)
//
#include <hip/hip_runtime.h>
#include <math.h>

// HiPPO-LegS reconstruction: out = sum_{k=1..256} coef[k-1]*sqrt(2k+1)*P_k(x),
// x = 2t/curr_t - 1.
//
// Model (fit R1-R7): dur_us = ~58.6us harness floor + kernel. R7 (2-op
// Clenshaw, 1 point/thread) = ~5.4us kernel vs ~3.4-3.8us VALU floor.
// Theory for the gap: broadcast ds_read_b128 of w4[] -- DS pipe is per-CU
// shared by 4 SIMDs; at 32 waves/CU x 64 reads = 2048 DS ops/CU @ ~6cyc
// = 12.3K cyc > the 8192-cyc VALU window -> DS-bound at ~5.1us (matches).
//
// R8: 4 points/thread (float4 in/out). DS reads per point /4 (512 DS
// ops/CU ~ 3K cyc, below VALU floor); per-wave ILP x4 (4 independent
// Clenshaw chains) so 2 waves/SIMD saturates VALU; grid = 512 blocks =
// exactly 2 blocks/CU, all resident, no tail. w-setup runs 512x not 2048x.
//
//   Clenshaw on rescaled basis S_{d+1} = 2x*S_d - beta_d*S_{d-1}:
//   b_k = w'_k + 2x*b_{k+1} - beta_{k+1}*b_{k+2};  f = x*b_1 - (2/3)*b_2
//   beta_d = 4d^2/(4d^2-1) (compile-time), w'_k = coef[k-1]*sqrt(2k+1)*g_k

#define NDEG 256

// g_i = 2*C(2i,i)/4^i: exact for i<8, 4-term Stirling beyond (rel < 1e-7).
__device__ __forceinline__ float g_of(int i) {
    const float fi = (float)i;
    float r = 2.0f * rsqrtf(3.14159265358979f * fi);
    float inv = 1.0f / fi;
    float corr = 1.0f + inv * (-0.125f + inv * (0.0078125f + inv * 0.0048828125f));
    float g = r * corr;
    g = (i == 1) ? 1.0f          : g;
    g = (i == 2) ? 0.75f         : g;
    g = (i == 3) ? 0.625f        : g;
    g = (i == 4) ? 0.546875f     : g;
    g = (i == 5) ? 0.4921875f    : g;
    g = (i == 6) ? 0.451171875f  : g;
    g = (i == 7) ? 0.4189453125f : g;
    return g;
}

// -beta_{d} as a compile-time-foldable constant.
constexpr float nbeta(int d) {
    double dd = (double)d;
    return (float)(-(4.0 * dd * dd) / (4.0 * dd * dd - 1.0));
}

// One Clenshaw degree for 4 independent points. tt_p = w + nb*b2_p (one
// s_mov of nb to SGPR + 4x VOP3 v_fma, SALU is free); bn_p = U_p*b1_p + tt_p
// (VOP2 v_fmac). 8 FMAs issued with 4-way ILP; only the bn chain is
// latency-critical (4cyc), 4 chains per wave fully cover it.
__device__ __forceinline__ void step4(
    const float U0, const float U1, const float U2, const float U3,
    float& b10, float& b20, float& b11, float& b21,
    float& b12, float& b22, float& b13, float& b23,
    const float nb, const float w)
{
    float t0 = fmaf(nb, b20, w);
    float t1 = fmaf(nb, b21, w);
    float t2 = fmaf(nb, b22, w);
    float t3 = fmaf(nb, b23, w);
    float n0 = fmaf(U0, b10, t0);
    float n1 = fmaf(U1, b11, t1);
    float n2 = fmaf(U2, b12, t2);
    float n3 = fmaf(U3, b13, t3);
    b20 = b10; b21 = b11; b22 = b12; b23 = b13;
    b10 = n0;  b11 = n1;  b12 = n2;  b13 = n3;
}

#define STEP4(NB, W) step4(U0, U1, U2, U3, \
    b10, b20, b11, b21, b12, b22, b13, b23, (NB), (W))

__global__ __launch_bounds__(256, 2) void hippo_kernel(
    const float* __restrict__ t,
    const float* __restrict__ coef,
    const int* __restrict__ curr_t,
    float* __restrict__ out,
    int n)
{
    // w'[k], k=1..256: w4[j] = {w'(4j+1), w'(4j+2), w'(4j+3), w'(4j+4)}
    __shared__ float4 w4[NDEG / 4];
    float* wf = (float*)w4;

    const int tid = threadIdx.x;
    {
        const int k = tid + 1;
        wf[tid] = coef[tid] * sqrtf(2.0f * (float)k + 1.0f) * g_of(k);
    }
    __syncthreads();

    const int gid  = blockIdx.x * 256 + tid;  // float4-group index
    const int base = gid * 4;
    const float s = 2.0f / (float)curr_t[0];

    float4 tv;
    if (base + 3 < n) {
        tv = reinterpret_cast<const float4*>(t)[gid];
    } else {  // tail safety (never taken at n=524288)
        tv.x = (base + 0 < n) ? t[base + 0] : 0.0f;
        tv.y = (base + 1 < n) ? t[base + 1] : 0.0f;
        tv.z = (base + 2 < n) ? t[base + 2] : 0.0f;
        tv.w = (base + 3 < n) ? t[base + 3] : 0.0f;
    }

    const float x0 = fmaf(tv.x, s, -1.0f);
    const float x1 = fmaf(tv.y, s, -1.0f);
    const float x2 = fmaf(tv.z, s, -1.0f);
    const float x3 = fmaf(tv.w, s, -1.0f);
    const float U0 = 2.0f * x0, U1 = 2.0f * x1;
    const float U2 = 2.0f * x2, U3 = 2.0f * x3;

    float b10 = 0.0f, b20 = 0.0f;   // b_258 = b_257 = 0, per point
    float b11 = 0.0f, b21 = 0.0f;
    float b12 = 0.0f, b22 = 0.0f;
    float b13 = 0.0f, b23 = 0.0f;

#pragma unroll
    for (int j = 63; j >= 0; --j) {
        const float4 c = w4[j];   // broadcast ds_read_b128, 1 per 4 degrees
        STEP4(nbeta(4 * j + 5), c.w);  // degree 4j+4
        STEP4(nbeta(4 * j + 4), c.z);  // degree 4j+3
        STEP4(nbeta(4 * j + 3), c.y);  // degree 4j+2
        STEP4(nbeta(4 * j + 2), c.x);  // degree 4j+1
    }

    // f = x*b_1 - beta_1*S_0*b_2 = x*b1 - (4/3)*(1/2)*b2
    float4 ov;
    ov.x = fmaf(x0, b10, -0.66666666666667f * b20);
    ov.y = fmaf(x1, b11, -0.66666666666667f * b21);
    ov.z = fmaf(x2, b12, -0.66666666666667f * b22);
    ov.w = fmaf(x3, b13, -0.66666666666667f * b23);

    if (base + 3 < n) {
        reinterpret_cast<float4*>(out)[gid] = ov;
    } else {
        if (base + 0 < n) out[base + 0] = ov.x;
        if (base + 1 < n) out[base + 1] = ov.y;
        if (base + 2 < n) out[base + 2] = ov.z;
        if (base + 3 < n) out[base + 3] = ov.w;
    }
}

extern "C" void kernel_launch(void* const* d_in, const int* in_sizes, int n_in,
                              void* d_out, int out_size, void* d_ws, size_t ws_size,
                              hipStream_t stream)
{
    const float* t      = (const float*)d_in[0];
    const float* coef   = (const float*)d_in[1];
    const int*   curr_t = (const int*)d_in[2];
    float*       out    = (float*)d_out;

    int n = in_sizes[0];                   // 524288
    int blocks = (n + 1023) / 1024;        // 512 blocks = 2 blocks/CU, all resident
    hippo_kernel<<<blocks, 256, 0, stream>>>(t, coef, curr_t, out, n);
}